// Round 1
// baseline (13441.779 us; speedup 1.0000x reference)
//
#include <hip/hip_runtime.h>

typedef __bf16 bf16;
typedef __attribute__((ext_vector_type(8))) __bf16 bf16x8;
typedef __attribute__((ext_vector_type(4))) float f32x4;

#define GLOBAL_AS __attribute__((address_space(1)))
#define LDS_AS __attribute__((address_space(3)))

__device__ __forceinline__ void gload_lds16(const void* g, void* l) {
  __builtin_amdgcn_global_load_lds((const GLOBAL_AS void*)g, (LDS_AS void*)l, 16, 0, 0);
}

__device__ __forceinline__ f32x4 mfma16(bf16x8 a, bf16x8 b, f32x4 c) {
  return __builtin_amdgcn_mfma_f32_16x16x32_bf16(a, b, c, 0, 0, 0);
}

// ---------------- constants ----------------
#define T_SEQ 300
#define NBATCH 32
#define DIN 320
#define NH 1024
#define NG 4096              // 4*NH
#define MROWS 9600           // T_SEQ*NBATCH
#define OUT_Y 19660800       // T*B*2H
#define HN_SZ 196608         // 6*32*1024

// ---------------- f32 -> bf16 convert ----------------
__global__ __launch_bounds__(256) void k_cvt(const float* __restrict__ src,
                                             bf16* __restrict__ dst, int n8) {
  int stride = gridDim.x * blockDim.x;
  for (int i = blockIdx.x * blockDim.x + threadIdx.x; i < n8; i += stride) {
    const float* s = src + (size_t)i * 8;
    f32x4 a = *(const f32x4*)s;
    f32x4 b = *(const f32x4*)(s + 4);
    bf16x8 o;
#pragma unroll
    for (int j = 0; j < 4; ++j) { o[j] = (bf16)a[j]; o[j + 4] = (bf16)b[j]; }
    *(bf16x8*)(dst + (size_t)i * 8) = o;
  }
}

// ---------------- bias sums: bsum[l][dir][4096] = b_ih + b_hh ----------------
__global__ __launch_bounds__(256) void k_bsum(const float* __restrict__ bih0,
                                              const float* __restrict__ bhh0,
                                              const float* __restrict__ bihL,
                                              const float* __restrict__ bhhL,
                                              float* __restrict__ bsum) {
  int i = blockIdx.x * 256 + threadIdx.x;  // n = 6*4096 = 24576
  if (i < 2 * NG) bsum[i] = bih0[i] + bhh0[i];
  else            bsum[i] = bihL[i - 2 * NG] + bhhL[i - 2 * NG];
}

// ---------------- GX GEMM: gx = A[M,K] * W[8192,K]^T + bias ----------------
// A bf16 row-major [9600][K]; W bf16 row-major [2*4096][K] (dir-major);
// out: gx bf16 [2][300][32][4096]. grid = (64, 75), block = 256.
__global__ __launch_bounds__(256) void k_gemm_gx(const bf16* __restrict__ A,
                                                 const bf16* __restrict__ Bw,
                                                 const float* __restrict__ bias,
                                                 bf16* __restrict__ gxout, int K) {
  __shared__ bf16 As[128 * 32];
  __shared__ bf16 Bs[128 * 32];
  const int t = threadIdx.x;
  const int m0 = blockIdx.y * 128, n0 = blockIdx.x * 128;
  const int lane = t & 63, wid = t >> 6;
  const int wr = wid >> 1, wc = wid & 1;
  const int fr = lane & 15, fq = lane >> 4;
  f32x4 acc[4][4] = {};
  for (int k0 = 0; k0 < K; k0 += 32) {
#pragma unroll
    for (int r = 0; r < 2; ++r) {
      int idx = r * 256 + t;
      int row = idx >> 2, kk = (idx & 3) * 8;
      gload_lds16(A + (size_t)(m0 + row) * K + k0 + kk, As + (size_t)idx * 8);
      gload_lds16(Bw + (size_t)(n0 + row) * K + k0 + kk, Bs + (size_t)idx * 8);
    }
    asm volatile("s_waitcnt vmcnt(0)" ::: "memory");
    __syncthreads();
    bf16x8 af[4], bf_[4];
#pragma unroll
    for (int i2 = 0; i2 < 4; ++i2) {
      af[i2]  = *(const bf16x8*)(As + (wr * 64 + i2 * 16 + fr) * 32 + fq * 8);
      bf_[i2] = *(const bf16x8*)(Bs + (wc * 64 + i2 * 16 + fr) * 32 + fq * 8);
    }
#pragma unroll
    for (int mi = 0; mi < 4; ++mi)
#pragma unroll
      for (int ni = 0; ni < 4; ++ni)
        acc[mi][ni] = mfma16(af[mi], bf_[ni], acc[mi][ni]);
    __syncthreads();
  }
  // epilogue: add bias, scatter to gx[dir][t][b][4096]
#pragma unroll
  for (int ni = 0; ni < 4; ++ni) {
    int col = n0 + wc * 64 + ni * 16 + fr;
    float bv = bias[col];
    int dir = col >> 12, g = col & (NG - 1);
#pragma unroll
    for (int mi = 0; mi < 4; ++mi) {
#pragma unroll
      for (int j = 0; j < 4; ++j) {
        int row = m0 + wr * 64 + mi * 16 + fq * 4 + j;
        gxout[((size_t)dir * MROWS + row) * NG + g] = (bf16)(acc[mi][ni][j] + bv);
      }
    }
  }
}

// ---------------- per-layer state init (cn = hn = h0 per reference) ----------------
__global__ __launch_bounds__(256) void k_init(const float* __restrict__ h0,
                                              bf16* __restrict__ hbf_p0,
                                              float* __restrict__ hf32,
                                              float* __restrict__ cst, int layer) {
  int i = blockIdx.x * 256 + threadIdx.x;  // n = 2*32*1024 = 65536
  float v = h0[(size_t)layer * 65536 + i];
  hbf_p0[i] = (bf16)v;
  hf32[i] = v;
  cst[i] = v;
}

// ---------------- one recurrence step (both directions) ----------------
// grid = 128 (dir = bx>>6, 16 hidden units per block), block = 256 (wave = gate).
__global__ __launch_bounds__(256) void k_step(const bf16* __restrict__ whh_l,
                                              const bf16* __restrict__ gx,
                                              const bf16* __restrict__ h_in,
                                              bf16* __restrict__ h_out,
                                              float* __restrict__ hf32,
                                              float* __restrict__ cst,
                                              bf16* __restrict__ ynext,
                                              float* __restrict__ dout_y,
                                              int t_fwd) {
  const int tid = threadIdx.x;
  const int dir = blockIdx.x >> 6;
  const int u0 = (blockIdx.x & 63) << 4;
  const int t = dir ? (T_SEQ - 1 - t_fwd) : t_fwd;
  const int g = tid >> 6;
  const int lane = tid & 63, fr = lane & 15, fq = lane >> 4;

  const bf16* W  = whh_l + ((size_t)dir * NG + g * NH + u0 + fr) * NH;
  const bf16* Hp = h_in + (size_t)dir * (NBATCH * NH) + (size_t)fr * NH;

  f32x4 acc0 = {0.f, 0.f, 0.f, 0.f}, acc1 = {0.f, 0.f, 0.f, 0.f};
  // 8-deep register pipeline over 32 K-iters (K=1024, BK=32)
  bf16x8 wb[8], ha[8], hb[8];
#pragma unroll
  for (int s = 0; s < 8; ++s) {
    int k = s * 32 + fq * 8;
    wb[s] = *(const bf16x8*)(W + k);
    ha[s] = *(const bf16x8*)(Hp + k);
    hb[s] = *(const bf16x8*)(Hp + 16 * NH + k);
  }
#pragma unroll
  for (int it = 0; it < 32; ++it) {
    int s = it & 7;
    acc0 = mfma16(ha[s], wb[s], acc0);
    acc1 = mfma16(hb[s], wb[s], acc1);
    if (it < 24) {
      int k = (it + 8) * 32 + fq * 8;
      wb[s] = *(const bf16x8*)(W + k);
      ha[s] = *(const bf16x8*)(Hp + k);
      hb[s] = *(const bf16x8*)(Hp + 16 * NH + k);
    }
  }

  // add gx (biases already folded in) and exchange gates via LDS
  __shared__ float glds[4][32][16];
  const bf16* gxp = gx + ((size_t)dir * T_SEQ + t) * (NBATCH * NG) + (size_t)g * NH + u0 + fr;
#pragma unroll
  for (int j = 0; j < 4; ++j) {
    glds[g][fq * 4 + j][fr]      = acc0[j] + (float)gxp[(size_t)(fq * 4 + j) * NG];
    glds[g][16 + fq * 4 + j][fr] = acc1[j] + (float)gxp[(size_t)(16 + fq * 4 + j) * NG];
  }
  __syncthreads();

  // pointwise: 256 threads handle 512 (b,u) pairs
  const int u = tid & 15, su = u0 + u;
#pragma unroll
  for (int half = 0; half < 2; ++half) {
    int b = (tid >> 4) + half * 16;
    float iv = glds[0][b][u], fv = glds[1][b][u], gv = glds[2][b][u], ov = glds[3][b][u];
    iv = fminf(fmaxf(__builtin_fmaf(0.2f, iv, 0.5f), 0.f), 1.f);
    fv = fminf(fmaxf(__builtin_fmaf(0.2f, fv, 0.5f), 0.f), 1.f);
    gv = fminf(fmaxf(gv, -1.f), 1.f);
    ov = fminf(fmaxf(__builtin_fmaf(0.2f, ov, 0.5f), 0.f), 1.f);
    size_t sidx = (size_t)dir * (NBATCH * NH) + (size_t)b * NH + su;
    float c = fv * cst[sidx] + iv * gv;
    cst[sidx] = c;
    float h = ov * fminf(fmaxf(c, -1.f), 1.f);
    hf32[sidx] = h;
    h_out[sidx] = (bf16)h;
    size_t yi = ((size_t)t * NBATCH + b) * (2 * NH) + (size_t)dir * NH + su;
    ynext[yi] = (bf16)h;
    if (dout_y) dout_y[yi] = h;
  }
}

// ---------------- copy final (h,c) of a layer into d_out tail ----------------
__global__ __launch_bounds__(256) void k_states_out(const float* __restrict__ hf32,
                                                    const float* __restrict__ cst,
                                                    float* __restrict__ dout, int layer) {
  int i = blockIdx.x * 256 + threadIdx.x;  // 65536
  dout[(size_t)OUT_Y + (size_t)layer * 65536 + i] = hf32[i];
  dout[(size_t)OUT_Y + HN_SZ + (size_t)layer * 65536 + i] = cst[i];
}

// ---------------- host launcher ----------------
extern "C" void kernel_launch(void* const* d_in, const int* in_sizes, int n_in,
                              void* d_out, int out_size, void* d_ws, size_t ws_size,
                              hipStream_t stream) {
  const float* x     = (const float*)d_in[0];
  const float* h0    = (const float*)d_in[1];
  // d_in[2] = c0: unused (reference init bug: cn = hn = h0)
  const float* w_ih0 = (const float*)d_in[3];
  const float* w_hh0 = (const float*)d_in[4];
  const float* b_ih0 = (const float*)d_in[5];
  const float* b_hh0 = (const float*)d_in[6];
  const float* w_ihL = (const float*)d_in[7];
  const float* w_hhL = (const float*)d_in[8];
  const float* b_ihL = (const float*)d_in[9];
  const float* b_hhL = (const float*)d_in[10];
  float* dout = (float*)d_out;
  char* ws = (char*)d_ws;

  // ---- workspace carve (bytes, all 512-aligned) ----
  const size_t OFF_XB   = 0;                         // bf16 [9600][320]
  const size_t OFF_WIH0 = 6144000;                   // bf16 [8192][320]
  const size_t OFF_WIHL = 11386880;                  // bf16 [2][8192][2048]
  const size_t OFF_WHH  = 78495744;                  // bf16 [6][4096][1024]
  const size_t OFF_BSUM = 128827392;                 // f32  [6][4096]
  const size_t OFF_GX   = 128925696;                 // bf16 [2][300][32][4096]
  const size_t OFF_Y0   = 286212096;                 // bf16 [9600][2048]
  const size_t OFF_Y1   = 325533696;                 // bf16 [9600][2048]
  const size_t OFF_HBF  = 364855296;                 // bf16 [2 parity][2][32][1024]
  const size_t OFF_HF32 = 365117440;                 // f32  [2][32][1024]
  const size_t OFF_CST  = 365379584;                 // f32  [2][32][1024]

  bf16*  xb    = (bf16*)(ws + OFF_XB);
  bf16*  wih0b = (bf16*)(ws + OFF_WIH0);
  bf16*  wihLb = (bf16*)(ws + OFF_WIHL);
  bf16*  whhb  = (bf16*)(ws + OFF_WHH);
  float* bsum  = (float*)(ws + OFF_BSUM);
  bf16*  gx    = (bf16*)(ws + OFF_GX);
  bf16*  y0    = (bf16*)(ws + OFF_Y0);
  bf16*  y1    = (bf16*)(ws + OFF_Y1);
  bf16*  hbf   = (bf16*)(ws + OFF_HBF);
  float* hf32  = (float*)(ws + OFF_HF32);
  float* cst   = (float*)(ws + OFF_CST);

  auto cvt = [&](const float* s, bf16* d, size_t n) {
    int n8 = (int)(n / 8);
    int grid = (n8 + 255) / 256; if (grid > 2048) grid = 2048;
    k_cvt<<<grid, 256, 0, stream>>>(s, d, n8);
  };

  // ---- one-time (per-call) conversions ----
  cvt(x,     xb,    (size_t)MROWS * DIN);                    // 3,072,000
  cvt(w_ih0, wih0b, (size_t)2 * NG * DIN);                   // 2,621,440
  cvt(w_ihL, wihLb, (size_t)2 * 2 * NG * 2048);              // 33,554,432
  cvt(w_hh0, whhb,  (size_t)2 * NG * NH);                    // 8,388,608
  cvt(w_hhL, whhb + (size_t)2 * NG * NH, (size_t)4 * NG * NH); // 16,777,216
  k_bsum<<<96, 256, 0, stream>>>(b_ih0, b_hh0, b_ihL, b_hhL, bsum);

  // ---- layers ----
  for (int l = 0; l < 3; ++l) {
    const bf16* A = (l == 0) ? xb : (l == 1 ? y0 : y1);
    int K = (l == 0) ? DIN : 2048;
    const bf16* Bw = (l == 0) ? wih0b : (wihLb + (size_t)(l - 1) * 2 * NG * 2048);
    k_gemm_gx<<<dim3(64, 75), 256, 0, stream>>>(A, Bw, bsum + (size_t)l * 2 * NG, gx, K);

    k_init<<<256, 256, 0, stream>>>(h0, hbf, hf32, cst, l);

    const bf16* whh_l = whhb + (size_t)l * 2 * NG * NH;
    bf16* ynext = (l == 0) ? y0 : (l == 1 ? y1 : y0);
    float* dy = (l == 2) ? dout : nullptr;
    for (int t = 0; t < T_SEQ; ++t) {
      int p = t & 1;
      k_step<<<128, 256, 0, stream>>>(whh_l, gx,
                                      hbf + (size_t)p * 65536,
                                      hbf + (size_t)(p ^ 1) * 65536,
                                      hf32, cst, ynext, dy, t);
    }
    k_states_out<<<256, 256, 0, stream>>>(hf32, cst, dout, l);
  }
  (void)in_sizes; (void)n_in; (void)out_size; (void)ws_size;
}

// Round 2
// 10663.006 us; speedup vs baseline: 1.2606x; 1.2606x over previous
//
#include <hip/hip_runtime.h>

typedef __bf16 bf16;
typedef __attribute__((ext_vector_type(8))) __bf16 bf16x8;
typedef __attribute__((ext_vector_type(4))) float f32x4;

#define GLOBAL_AS __attribute__((address_space(1)))
#define LDS_AS __attribute__((address_space(3)))

__device__ __forceinline__ void gload_lds16(const void* g, void* l) {
  __builtin_amdgcn_global_load_lds((const GLOBAL_AS void*)g, (LDS_AS void*)l, 16, 0, 0);
}
// cache-bypassing variant (sc0|sc1) for cross-XCD-fresh h reads
__device__ __forceinline__ void gload_lds16_cc(const void* g, void* l) {
  __builtin_amdgcn_global_load_lds((const GLOBAL_AS void*)g, (LDS_AS void*)l, 16, 0, 0x11);
}

__device__ __forceinline__ f32x4 mfma16(bf16x8 a, bf16x8 b, f32x4 c) {
  return __builtin_amdgcn_mfma_f32_16x16x32_bf16(a, b, c, 0, 0, 0);
}

// ---------------- constants ----------------
#define T_SEQ 300
#define NBATCH 32
#define DIN 320
#define NH 1024
#define NG 4096              // 4*NH
#define MROWS 9600           // T_SEQ*NBATCH
#define OUT_Y 19660800       // T*B*2H
#define HN_SZ 196608         // 6*32*1024

// ---------------- f32 -> bf16 convert ----------------
__global__ __launch_bounds__(256) void k_cvt(const float* __restrict__ src,
                                             bf16* __restrict__ dst, int n8) {
  int stride = gridDim.x * blockDim.x;
  for (int i = blockIdx.x * blockDim.x + threadIdx.x; i < n8; i += stride) {
    const float* s = src + (size_t)i * 8;
    f32x4 a = *(const f32x4*)s;
    f32x4 b = *(const f32x4*)(s + 4);
    bf16x8 o;
#pragma unroll
    for (int j = 0; j < 4; ++j) { o[j] = (bf16)a[j]; o[j + 4] = (bf16)b[j]; }
    *(bf16x8*)(dst + (size_t)i * 8) = o;
  }
}

// ---------------- bias sums: bsum[l][dir][4096] = b_ih + b_hh ----------------
__global__ __launch_bounds__(256) void k_bsum(const float* __restrict__ bih0,
                                              const float* __restrict__ bhh0,
                                              const float* __restrict__ bihL,
                                              const float* __restrict__ bhhL,
                                              float* __restrict__ bsum) {
  int i = blockIdx.x * 256 + threadIdx.x;  // n = 6*4096 = 24576
  if (i < 2 * NG) bsum[i] = bih0[i] + bhh0[i];
  else            bsum[i] = bihL[i - 2 * NG] + bhhL[i - 2 * NG];
}

// ---------------- GX GEMM: gx = A[M,K] * W[8192,K]^T + bias ----------------
__global__ __launch_bounds__(256) void k_gemm_gx(const bf16* __restrict__ A,
                                                 const bf16* __restrict__ Bw,
                                                 const float* __restrict__ bias,
                                                 bf16* __restrict__ gxout, int K) {
  __shared__ bf16 As[128 * 32];
  __shared__ bf16 Bs[128 * 32];
  const int t = threadIdx.x;
  const int m0 = blockIdx.y * 128, n0 = blockIdx.x * 128;
  const int lane = t & 63, wid = t >> 6;
  const int wr = wid >> 1, wc = wid & 1;
  const int fr = lane & 15, fq = lane >> 4;
  f32x4 acc[4][4] = {};
  for (int k0 = 0; k0 < K; k0 += 32) {
#pragma unroll
    for (int r = 0; r < 2; ++r) {
      int idx = r * 256 + t;
      int row = idx >> 2, kk = (idx & 3) * 8;
      gload_lds16(A + (size_t)(m0 + row) * K + k0 + kk, As + (size_t)idx * 8);
      gload_lds16(Bw + (size_t)(n0 + row) * K + k0 + kk, Bs + (size_t)idx * 8);
    }
    asm volatile("s_waitcnt vmcnt(0)" ::: "memory");
    __syncthreads();
    bf16x8 af[4], bf_[4];
#pragma unroll
    for (int i2 = 0; i2 < 4; ++i2) {
      af[i2]  = *(const bf16x8*)(As + (wr * 64 + i2 * 16 + fr) * 32 + fq * 8);
      bf_[i2] = *(const bf16x8*)(Bs + (wc * 64 + i2 * 16 + fr) * 32 + fq * 8);
    }
#pragma unroll
    for (int mi = 0; mi < 4; ++mi)
#pragma unroll
      for (int ni = 0; ni < 4; ++ni)
        acc[mi][ni] = mfma16(af[mi], bf_[ni], acc[mi][ni]);
    __syncthreads();
  }
#pragma unroll
  for (int ni = 0; ni < 4; ++ni) {
    int col = n0 + wc * 64 + ni * 16 + fr;
    float bv = bias[col];
    int dir = col >> 12, g = col & (NG - 1);
#pragma unroll
    for (int mi = 0; mi < 4; ++mi) {
#pragma unroll
      for (int j = 0; j < 4; ++j) {
        int row = m0 + wr * 64 + mi * 16 + fq * 4 + j;
        gxout[((size_t)dir * MROWS + row) * NG + g] = (bf16)(acc[mi][ni][j] + bv);
      }
    }
  }
}

// ---------------- per-layer init: h broadcast buffer (par 0) + flags ----------------
__global__ __launch_bounds__(256) void k_init(const float* __restrict__ h0,
                                              bf16* __restrict__ hbuf,
                                              int* __restrict__ flags, int layer) {
  int i = blockIdx.x * 256 + threadIdx.x;  // 65536 = [2 dir][32][1024]
  hbuf[i] = (bf16)h0[(size_t)layer * 65536 + i];
  if (blockIdx.x == 0 && threadIdx.x < 64) flags[threadIdx.x] = 0;
}

// ---------------- persistent recurrence: one launch per layer ----------------
// grid = 64 blocks x 512 threads. dir = bid>>5; block owns 32 hidden units.
// Wave w: gate g=w>>1, unit-half uh=w&1 -> 16 gate-rows, W_hh slice in 128 VGPRs.
__global__ __launch_bounds__(512, 2) void k_rec(
    const bf16* __restrict__ whh,   // [2][4096][1024] (this layer)
    const bf16* __restrict__ gx,    // [2][9600][4096] bf16, biases folded
    const float* __restrict__ h0,   // [6][32][1024]
    bf16* __restrict__ hbuf,        // [2 par][2 dir][32][1024]
    int* __restrict__ flags,        // [64], zeroed by k_init
    bf16* __restrict__ yout,        // [9600][2048] or null (layer 2)
    float* __restrict__ dout,
    int layer) {
  __shared__ char smem_[65536];
  bf16* hs = (bf16*)smem_;        // staged h, XOR-swizzled rows
  float* glds = (float*)smem_;    // aliased after compute: [4][2][32 b][17]

  const int tid = threadIdx.x;
  const int bid = blockIdx.x;
  const int dir = bid >> 5;
  const int u0 = (bid & 31) << 5;
  const int w = tid >> 6, lane = tid & 63;
  const int fr = lane & 15, fq = lane >> 4;
  const int g = w >> 1, uh = w & 1;

  // ---- weights -> registers (16 rows x 1024 bf16 per wave = 128 VGPR/lane) ----
  bf16x8 wreg[32];
  {
    const bf16* Wp = whh + ((size_t)dir * 4096 + g * 1024 + u0 + uh * 16 + fr) * 1024 + fq * 8;
#pragma unroll
    for (int it = 0; it < 32; ++it) wreg[it] = *(const bf16x8*)(Wp + it * 32);
  }

  // ---- cell state in registers; c init = h0 (reference's cn=hn bug) ----
  const int b_pt = tid >> 4;           // batch 0..31
  const int ul_pt = (tid & 15) << 1;   // local unit 0,2,..,30
  const int ug_pt = u0 + ul_pt;
  const size_t soff = ((size_t)layer * 2 + dir) * 32768 + (size_t)b_pt * 1024 + ug_pt;
  float c0 = h0[soff], c1 = h0[soff + 1];
  float hl0 = 0.f, hl1 = 0.f;

#pragma unroll 1
  for (int t = 0; t < T_SEQ; ++t) {
    // ---- barrier: all same-dir blocks published h(t-1) ----
    if (tid < 32) {
      while (__hip_atomic_load(&flags[dir * 32 + tid], __ATOMIC_RELAXED,
                               __HIP_MEMORY_SCOPE_AGENT) < t) {}
    }
    __syncthreads();
    __builtin_amdgcn_fence(__ATOMIC_ACQUIRE, "agent");

    // ---- stage h(dir) 64KB -> LDS, swizzle via pre-swizzled global source ----
    const char* hsrc = (const char*)hbuf + (((size_t)(t & 1) * 2 + dir) << 16);
#pragma unroll
    for (int r = 0; r < 8; ++r) {
      int d = r * 8192 + tid * 16;            // LDS dest byte (linear)
      int row = d >> 11;                      // batch row (2048B rows)
      int colb = d & 2047;
      int scol = colb ^ ((row & 7) << 4);     // inverse swizzle on source
      gload_lds16_cc(hsrc + row * 2048 + scol, (char*)hs + d);
    }
    asm volatile("s_waitcnt vmcnt(0)" ::: "memory");
    __syncthreads();

    // ---- matvec: 64 MFMA from LDS(h) x VGPR(W) ----
    f32x4 acc0 = {0.f, 0.f, 0.f, 0.f}, acc1 = {0.f, 0.f, 0.f, 0.f};
    const int swz = (fr & 7) << 4;
    const char* hbase = (const char*)hs;
#pragma unroll
    for (int it = 0; it < 32; ++it) {
      bf16x8 ha  = *(const bf16x8*)(hbase + fr * 2048 + ((it * 64 + fq * 16) ^ swz));
      bf16x8 hbv = *(const bf16x8*)(hbase + (fr + 16) * 2048 + ((it * 64 + fq * 16) ^ swz));
      acc0 = mfma16(ha, wreg[it], acc0);
      acc1 = mfma16(hbv, wreg[it], acc1);
    }
    __syncthreads();  // all waves done with hs; glds aliases it

    // ---- add gx, exchange gates via LDS ----
    const int tseq = dir ? (T_SEQ - 1 - t) : t;
    const bf16* gxp = gx + ((size_t)dir * MROWS + (size_t)tseq * 32) * NG
                      + g * 1024 + u0 + uh * 16 + fr;
    const int gb = (g * 2 + uh) * 32;
#pragma unroll
    for (int j = 0; j < 4; ++j) {
      glds[(gb + fq * 4 + j) * 17 + fr]      = acc0[j] + (float)gxp[(size_t)(fq * 4 + j) * NG];
      glds[(gb + 16 + fq * 4 + j) * 17 + fr] = acc1[j] + (float)gxp[(size_t)(16 + fq * 4 + j) * NG];
    }
    __syncthreads();

    // ---- pointwise: 2 (b,u) pairs per thread, c in regs ----
    float hv[2]; float cc[2] = {c0, c1};
#pragma unroll
    for (int q = 0; q < 2; ++q) {
      int ul = ul_pt + q, uhh = ul >> 4, ufr = ul & 15;
      int base = (uhh * 32 + b_pt) * 17 + ufr;     // gate stride = 2*32*17
      float iv = glds[base];
      float fv = glds[base + 2 * 32 * 17];
      float gv = glds[base + 4 * 32 * 17];
      float ov = glds[base + 6 * 32 * 17];
      iv = fminf(fmaxf(__builtin_fmaf(0.2f, iv, 0.5f), 0.f), 1.f);
      fv = fminf(fmaxf(__builtin_fmaf(0.2f, fv, 0.5f), 0.f), 1.f);
      gv = fminf(fmaxf(gv, -1.f), 1.f);
      ov = fminf(fmaxf(__builtin_fmaf(0.2f, ov, 0.5f), 0.f), 1.f);
      float c = fv * cc[q] + iv * gv;
      cc[q] = c;
      hv[q] = ov * fminf(fmaxf(c, -1.f), 1.f);
    }
    c0 = cc[0]; c1 = cc[1]; hl0 = hv[0]; hl1 = hv[1];

    // ---- publish h (write-through), y / dout ----
    unsigned hp;
    { union { bf16 h[2]; unsigned u; } pk; pk.h[0] = (bf16)hv[0]; pk.h[1] = (bf16)hv[1]; hp = pk.u; }
    volatile unsigned* hdst =
        (volatile unsigned*)((char*)hbuf + (((size_t)((t + 1) & 1) * 2 + dir) << 16))
        + (((size_t)b_pt * 1024 + ug_pt) >> 1);
    *hdst = hp;
    if (yout) {
      *(unsigned*)((char*)yout + (((size_t)tseq * 32 + b_pt) * 2048 + dir * 1024 + ug_pt) * 2) = hp;
    } else {
      float* yd = dout + ((size_t)tseq * 32 + b_pt) * 2048 + dir * 1024 + ug_pt;
      yd[0] = hv[0]; yd[1] = hv[1];
    }
    __syncthreads();  // drains vmcnt -> volatile h stores are at the coherence point
    if (tid == 0)
      __hip_atomic_store(&flags[bid], t + 1, __ATOMIC_RELEASE, __HIP_MEMORY_SCOPE_AGENT);
  }

  // ---- final (h,c) states from registers ----
  dout[OUT_Y + soff] = hl0;
  dout[OUT_Y + soff + 1] = hl1;
  dout[OUT_Y + HN_SZ + soff] = c0;
  dout[OUT_Y + HN_SZ + soff + 1] = c1;
}

// ---------------- host launcher ----------------
extern "C" void kernel_launch(void* const* d_in, const int* in_sizes, int n_in,
                              void* d_out, int out_size, void* d_ws, size_t ws_size,
                              hipStream_t stream) {
  const float* x     = (const float*)d_in[0];
  const float* h0    = (const float*)d_in[1];
  // d_in[2] = c0: unused (reference init bug: cn = hn = h0)
  const float* w_ih0 = (const float*)d_in[3];
  const float* w_hh0 = (const float*)d_in[4];
  const float* b_ih0 = (const float*)d_in[5];
  const float* b_hh0 = (const float*)d_in[6];
  const float* w_ihL = (const float*)d_in[7];
  const float* w_hhL = (const float*)d_in[8];
  const float* b_ihL = (const float*)d_in[9];
  const float* b_hhL = (const float*)d_in[10];
  float* dout = (float*)d_out;
  char* ws = (char*)d_ws;

  // ---- workspace carve (bytes) ----
  const size_t OFF_XB   = 0;                         // bf16 [9600][320]
  const size_t OFF_WIH0 = 6144000;                   // bf16 [8192][320]
  const size_t OFF_WIHL = 11386880;                  // bf16 [2][8192][2048]
  const size_t OFF_WHH  = 78495744;                  // bf16 [6][4096][1024]
  const size_t OFF_BSUM = 128827392;                 // f32  [6][4096]
  const size_t OFF_GX   = 128925696;                 // bf16 [2][9600][4096]
  const size_t OFF_Y0   = 286212096;                 // bf16 [9600][2048]
  const size_t OFF_Y1   = 325533696;                 // bf16 [9600][2048]
  const size_t OFF_HBF  = 364855296;                 // bf16 [2 par][2 dir][32][1024]
  const size_t OFF_FLG  = 365117440;                 // int  [64]

  bf16*  xb    = (bf16*)(ws + OFF_XB);
  bf16*  wih0b = (bf16*)(ws + OFF_WIH0);
  bf16*  wihLb = (bf16*)(ws + OFF_WIHL);
  bf16*  whhb  = (bf16*)(ws + OFF_WHH);
  float* bsum  = (float*)(ws + OFF_BSUM);
  bf16*  gx    = (bf16*)(ws + OFF_GX);
  bf16*  y0    = (bf16*)(ws + OFF_Y0);
  bf16*  y1    = (bf16*)(ws + OFF_Y1);
  bf16*  hbuf  = (bf16*)(ws + OFF_HBF);
  int*   flags = (int*)(ws + OFF_FLG);

  auto cvt = [&](const float* s, bf16* d, size_t n) {
    int n8 = (int)(n / 8);
    int grid = (n8 + 255) / 256; if (grid > 2048) grid = 2048;
    k_cvt<<<grid, 256, 0, stream>>>(s, d, n8);
  };

  cvt(x,     xb,    (size_t)MROWS * DIN);
  cvt(w_ih0, wih0b, (size_t)2 * NG * DIN);
  cvt(w_ihL, wihLb, (size_t)2 * 2 * NG * 2048);
  cvt(w_hh0, whhb,  (size_t)2 * NG * NH);
  cvt(w_hhL, whhb + (size_t)2 * NG * NH, (size_t)4 * NG * NH);
  k_bsum<<<96, 256, 0, stream>>>(b_ih0, b_hh0, b_ihL, b_hhL, bsum);

  for (int l = 0; l < 3; ++l) {
    const bf16* A = (l == 0) ? xb : (l == 1 ? y0 : y1);
    int K = (l == 0) ? DIN : 2048;
    const bf16* Bw = (l == 0) ? wih0b : (wihLb + (size_t)(l - 1) * 2 * NG * 2048);
    k_gemm_gx<<<dim3(64, 75), 256, 0, stream>>>(A, Bw, bsum + (size_t)l * 2 * NG, gx, K);

    k_init<<<256, 256, 0, stream>>>(h0, hbuf, flags, l);

    const bf16* whh_l = whhb + (size_t)l * 2 * NG * NH;
    bf16* yout = (l == 0) ? y0 : (l == 1 ? y1 : nullptr);
    k_rec<<<64, 512, 0, stream>>>(whh_l, gx, h0, hbuf, flags, yout, dout, l);
  }
  (void)in_sizes; (void)n_in; (void)out_size; (void)ws_size;
}

// Round 3
// 9183.145 us; speedup vs baseline: 1.4637x; 1.1611x over previous
//
#include <hip/hip_runtime.h>

typedef __bf16 bf16;
typedef __attribute__((ext_vector_type(8))) __bf16 bf16x8;
typedef __attribute__((ext_vector_type(4))) float f32x4;

#define GLOBAL_AS __attribute__((address_space(1)))
#define LDS_AS __attribute__((address_space(3)))

__device__ __forceinline__ void gload_lds16(const void* g, void* l) {
  __builtin_amdgcn_global_load_lds((const GLOBAL_AS void*)g, (LDS_AS void*)l, 16, 0, 0);
}
// cache-bypassing variant (sc0|sc1) for cross-XCD-fresh h reads
__device__ __forceinline__ void gload_lds16_cc(const void* g, void* l) {
  __builtin_amdgcn_global_load_lds((const GLOBAL_AS void*)g, (LDS_AS void*)l, 16, 0, 0x11);
}

__device__ __forceinline__ f32x4 mfma16(bf16x8 a, bf16x8 b, f32x4 c) {
  return __builtin_amdgcn_mfma_f32_16x16x32_bf16(a, b, c, 0, 0, 0);
}

// ---------------- constants ----------------
#define T_SEQ 300
#define NBATCH 32
#define DIN 320
#define NH 1024
#define NG 4096              // 4*NH
#define MROWS 9600           // T_SEQ*NBATCH
#define OUT_Y 19660800       // T*B*2H
#define HN_SZ 196608         // 6*32*1024

// ---------------- f32 -> bf16 convert ----------------
__global__ __launch_bounds__(256) void k_cvt(const float* __restrict__ src,
                                             bf16* __restrict__ dst, int n8) {
  int stride = gridDim.x * blockDim.x;
  for (int i = blockIdx.x * blockDim.x + threadIdx.x; i < n8; i += stride) {
    const float* s = src + (size_t)i * 8;
    f32x4 a = *(const f32x4*)s;
    f32x4 b = *(const f32x4*)(s + 4);
    bf16x8 o;
#pragma unroll
    for (int j = 0; j < 4; ++j) { o[j] = (bf16)a[j]; o[j + 4] = (bf16)b[j]; }
    *(bf16x8*)(dst + (size_t)i * 8) = o;
  }
}

// ---------------- bias sums: bsum[l][dir][4096] = b_ih + b_hh ----------------
__global__ __launch_bounds__(256) void k_bsum(const float* __restrict__ bih0,
                                              const float* __restrict__ bhh0,
                                              const float* __restrict__ bihL,
                                              const float* __restrict__ bhhL,
                                              float* __restrict__ bsum) {
  int i = blockIdx.x * 256 + threadIdx.x;  // n = 6*4096 = 24576
  if (i < 2 * NG) bsum[i] = bih0[i] + bhh0[i];
  else            bsum[i] = bihL[i - 2 * NG] + bhhL[i - 2 * NG];
}

// ---------------- GX GEMM: gxT[dir][t][gate][b][u] = A[M,K] * W[8192,K]^T + bias ----------------
__global__ __launch_bounds__(256) void k_gemm_gx(const bf16* __restrict__ A,
                                                 const bf16* __restrict__ Bw,
                                                 const float* __restrict__ bias,
                                                 bf16* __restrict__ gxout, int K) {
  __shared__ bf16 As[128 * 32];
  __shared__ bf16 Bs[128 * 32];
  const int t = threadIdx.x;
  const int m0 = blockIdx.y * 128, n0 = blockIdx.x * 128;
  const int lane = t & 63, wid = t >> 6;
  const int wr = wid >> 1, wc = wid & 1;
  const int fr = lane & 15, fq = lane >> 4;
  f32x4 acc[4][4] = {};
  for (int k0 = 0; k0 < K; k0 += 32) {
#pragma unroll
    for (int r = 0; r < 2; ++r) {
      int idx = r * 256 + t;
      int row = idx >> 2, kk = (idx & 3) * 8;
      gload_lds16(A + (size_t)(m0 + row) * K + k0 + kk, As + (size_t)idx * 8);
      gload_lds16(Bw + (size_t)(n0 + row) * K + k0 + kk, Bs + (size_t)idx * 8);
    }
    asm volatile("s_waitcnt vmcnt(0)" ::: "memory");
    __syncthreads();
    bf16x8 af[4], bf_[4];
#pragma unroll
    for (int i2 = 0; i2 < 4; ++i2) {
      af[i2]  = *(const bf16x8*)(As + (wr * 64 + i2 * 16 + fr) * 32 + fq * 8);
      bf_[i2] = *(const bf16x8*)(Bs + (wc * 64 + i2 * 16 + fr) * 32 + fq * 8);
    }
#pragma unroll
    for (int mi = 0; mi < 4; ++mi)
#pragma unroll
      for (int ni = 0; ni < 4; ++ni)
        acc[mi][ni] = mfma16(af[mi], bf_[ni], acc[mi][ni]);
    __syncthreads();
  }
  // epilogue: add bias, scatter to gxT[dir][t][g][b][u]
#pragma unroll
  for (int ni = 0; ni < 4; ++ni) {
    int col = n0 + wc * 64 + ni * 16 + fr;
    float bv = bias[col];
    int dir = col >> 12, grow = col & (NG - 1);
    int gg = grow >> 10, uu = grow & 1023;
    bf16* base = gxout + ((size_t)dir * 300 * 4 + gg) * 32768 + uu;
#pragma unroll
    for (int mi = 0; mi < 4; ++mi) {
#pragma unroll
      for (int j = 0; j < 4; ++j) {
        int row = m0 + wr * 64 + mi * 16 + fq * 4 + j;
        int tt = row >> 5, b = row & 31;
        base[(size_t)tt * 131072 + b * 1024] = (bf16)(acc[mi][ni][j] + bv);
      }
    }
  }
}

// ---------------- per-layer init: h broadcast buffer (par 0) + flags ----------------
__global__ __launch_bounds__(256) void k_init(const float* __restrict__ h0,
                                              bf16* __restrict__ hbuf,
                                              int* __restrict__ flags, int layer) {
  int i = blockIdx.x * 256 + threadIdx.x;  // 65536 = [2 dir][32][1024]
  hbuf[i] = (bf16)h0[(size_t)layer * 65536 + i];
  if (blockIdx.x == 0 && threadIdx.x < 64) flags[threadIdx.x] = 0;
}

// ---------------- persistent recurrence: one launch per layer ----------------
// grid = 64 blocks x 512 threads. dir = bid>>5; block owns 32 hidden units.
// Wave w: gate g=w>>1, unit-half uh=w&1 -> 16 gate-rows, W_hh slice pinned in 128 VGPRs.
__global__ __launch_bounds__(512, 1) void k_rec(
    const bf16* __restrict__ whh,   // [2][4096][1024] (this layer)
    const bf16* __restrict__ gxT,   // [2][300][4][32][1024] bf16, biases folded
    const float* __restrict__ h0,   // [6][32][1024]
    bf16* __restrict__ hbuf,        // [2 par][2 dir][32][1024]
    int* __restrict__ flags,        // [64], zeroed by k_init
    bf16* __restrict__ yout,        // [9600][2048] or null (layer 2)
    float* __restrict__ dout,
    int layer) {
  __shared__ char smem_[65536 + 8192];
  bf16* hs = (bf16*)smem_;              // staged h, XOR-swizzled rows
  float* glds = (float*)smem_;          // aliased after compute: [4][2][32 b][17]
  char* gxl = smem_ + 65536;            // gx tile [4 g][32 b][32 u] bf16 = 8KB

  const int tid = threadIdx.x;
  const int bid = blockIdx.x;
  const int dir = bid >> 5;
  const int u0 = (bid & 31) << 5;
  const int w = tid >> 6, lane = tid & 63;
  const int fr = lane & 15, fq = lane >> 4;
  const int g = w >> 1, uh = w & 1;

  // ---- weights -> registers, pinned against rematerialization ----
  f32x4 wf[32];
  {
    const bf16* Wp = whh + ((size_t)dir * 4096 + g * 1024 + u0 + uh * 16 + fr) * 1024 + fq * 8;
#pragma unroll
    for (int it = 0; it < 32; ++it) wf[it] = *(const f32x4*)(Wp + it * 32);
#pragma unroll
    for (int it = 0; it < 32; ++it) asm volatile("" : "+v"(wf[it]));
  }

  // ---- cell state in registers; c init = h0 (reference's cn=hn bug) ----
  const int b_pt = tid >> 4;           // batch 0..31
  const int ul_pt = (tid & 15) << 1;   // local unit 0,2,..,30
  const int ug_pt = u0 + ul_pt;
  const size_t soff = ((size_t)layer * 2 + dir) * 32768 + (size_t)b_pt * 1024 + ug_pt;
  float c0 = h0[soff], c1 = h0[soff + 1];
  float hl0 = 0.f, hl1 = 0.f;

  // gx DMA mapping: thread -> (gate, b, 16B quarter)
  const int gg = tid >> 7, sub = tid & 127;
  const size_t gx_base0 = ((size_t)dir * 300 * 4 + gg) * 32768
                          + (size_t)(sub >> 2) * 1024 + u0 + (sub & 3) * 8;

#pragma unroll 1
  for (int t = 0; t < T_SEQ; ++t) {
    const int tseq = dir ? (T_SEQ - 1 - t) : t;

    // ---- issue gx(t) DMA (8KB) — latency hides under the barrier poll ----
    gload_lds16(gxT + gx_base0 + (size_t)tseq * 131072, gxl + tid * 16);

    // ---- barrier: all same-dir blocks published h(t-1) ----
    if (tid < 32) {
      while (__hip_atomic_load(&flags[dir * 32 + tid], __ATOMIC_RELAXED,
                               __HIP_MEMORY_SCOPE_AGENT) < t)
        __builtin_amdgcn_s_sleep(1);
    }
    __syncthreads();
    __builtin_amdgcn_fence(__ATOMIC_ACQUIRE, "agent");

    // ---- stage h(dir) 64KB -> LDS, swizzle via pre-swizzled global source ----
    const char* hsrc = (const char*)hbuf + (((size_t)(t & 1) * 2 + dir) << 16);
#pragma unroll
    for (int r = 0; r < 8; ++r) {
      int d = r * 8192 + tid * 16;            // LDS dest byte (linear)
      int row = d >> 11;                      // batch row (2048B rows)
      int colb = d & 2047;
      int scol = colb ^ ((row & 7) << 4);     // inverse swizzle on source
      gload_lds16_cc(hsrc + row * 2048 + scol, (char*)hs + d);
    }
    asm volatile("s_waitcnt vmcnt(0)" ::: "memory");
    __syncthreads();

    // ---- matvec: 64 MFMA from LDS(h) x VGPR(W) ----
    f32x4 acc0 = {0.f, 0.f, 0.f, 0.f}, acc1 = {0.f, 0.f, 0.f, 0.f};
    const int swz = (fr & 7) << 4;
    const char* hbase = (const char*)hs;
#pragma unroll
    for (int it = 0; it < 32; ++it) {
      bf16x8 ha  = *(const bf16x8*)(hbase + fr * 2048 + ((it * 64 + fq * 16) ^ swz));
      bf16x8 hbv = *(const bf16x8*)(hbase + (fr + 16) * 2048 + ((it * 64 + fq * 16) ^ swz));
      bf16x8 wv = __builtin_bit_cast(bf16x8, wf[it]);
      acc0 = mfma16(ha, wv, acc0);
      acc1 = mfma16(hbv, wv, acc1);
    }
    __syncthreads();  // all waves done with hs; glds aliases it

    // ---- exchange gates via LDS (pure matvec acc) ----
    const int gb = (g * 2 + uh) * 32;
#pragma unroll
    for (int j = 0; j < 4; ++j) {
      glds[(gb + fq * 4 + j) * 17 + fr]      = acc0[j];
      glds[(gb + 16 + fq * 4 + j) * 17 + fr] = acc1[j];
    }
    __syncthreads();

    // ---- pointwise: 2 (b,u) pairs per thread; gx added from LDS; c in regs ----
    const bf16* gxb = (const bf16*)gxl;
    float hv[2]; float cc[2] = {c0, c1};
#pragma unroll
    for (int q = 0; q < 2; ++q) {
      int ul = ul_pt + q, uhh2 = ul >> 4, ufr = ul & 15;
      int base = (uhh2 * 32 + b_pt) * 17 + ufr;    // gate stride = 2*32*17
      float iv = glds[base]               + (float)gxb[(0 * 32 + b_pt) * 32 + ul];
      float fv = glds[base + 2 * 32 * 17] + (float)gxb[(1 * 32 + b_pt) * 32 + ul];
      float gv = glds[base + 4 * 32 * 17] + (float)gxb[(2 * 32 + b_pt) * 32 + ul];
      float ov = glds[base + 6 * 32 * 17] + (float)gxb[(3 * 32 + b_pt) * 32 + ul];
      iv = fminf(fmaxf(__builtin_fmaf(0.2f, iv, 0.5f), 0.f), 1.f);
      fv = fminf(fmaxf(__builtin_fmaf(0.2f, fv, 0.5f), 0.f), 1.f);
      gv = fminf(fmaxf(gv, -1.f), 1.f);
      ov = fminf(fmaxf(__builtin_fmaf(0.2f, ov, 0.5f), 0.f), 1.f);
      float c = fv * cc[q] + iv * gv;
      cc[q] = c;
      hv[q] = ov * fminf(fmaxf(c, -1.f), 1.f);
    }
    c0 = cc[0]; c1 = cc[1]; hl0 = hv[0]; hl1 = hv[1];

    // ---- publish h (write-through), drain, release flag, THEN y stores ----
    unsigned hp;
    { union { bf16 h[2]; unsigned u; } pk; pk.h[0] = (bf16)hv[0]; pk.h[1] = (bf16)hv[1]; hp = pk.u; }
    volatile unsigned* hdst =
        (volatile unsigned*)((char*)hbuf + (((size_t)((t + 1) & 1) * 2 + dir) << 16))
        + (((size_t)b_pt * 1024 + ug_pt) >> 1);
    *hdst = hp;
    asm volatile("s_waitcnt vmcnt(0)" ::: "memory");
    __syncthreads();
    if (tid == 0)
      __hip_atomic_store(&flags[bid], t + 1, __ATOMIC_RELEASE, __HIP_MEMORY_SCOPE_AGENT);
    if (yout) {
      *(unsigned*)((char*)yout + (((size_t)tseq * 32 + b_pt) * 2048 + dir * 1024 + ug_pt) * 2) = hp;
    } else {
      float* yd = dout + ((size_t)tseq * 32 + b_pt) * 2048 + dir * 1024 + ug_pt;
      yd[0] = hv[0]; yd[1] = hv[1];
    }
  }

  // ---- final (h,c) states from registers ----
  dout[OUT_Y + soff] = hl0;
  dout[OUT_Y + soff + 1] = hl1;
  dout[OUT_Y + HN_SZ + soff] = c0;
  dout[OUT_Y + HN_SZ + soff + 1] = c1;
}

// ---------------- host launcher ----------------
extern "C" void kernel_launch(void* const* d_in, const int* in_sizes, int n_in,
                              void* d_out, int out_size, void* d_ws, size_t ws_size,
                              hipStream_t stream) {
  const float* x     = (const float*)d_in[0];
  const float* h0    = (const float*)d_in[1];
  // d_in[2] = c0: unused (reference init bug: cn = hn = h0)
  const float* w_ih0 = (const float*)d_in[3];
  const float* w_hh0 = (const float*)d_in[4];
  const float* b_ih0 = (const float*)d_in[5];
  const float* b_hh0 = (const float*)d_in[6];
  const float* w_ihL = (const float*)d_in[7];
  const float* w_hhL = (const float*)d_in[8];
  const float* b_ihL = (const float*)d_in[9];
  const float* b_hhL = (const float*)d_in[10];
  float* dout = (float*)d_out;
  char* ws = (char*)d_ws;

  // ---- workspace carve (bytes) ----
  const size_t OFF_XB   = 0;                         // bf16 [9600][320]
  const size_t OFF_WIH0 = 6144000;                   // bf16 [8192][320]
  const size_t OFF_WIHL = 11386880;                  // bf16 [2][8192][2048]
  const size_t OFF_WHH  = 78495744;                  // bf16 [6][4096][1024]
  const size_t OFF_BSUM = 128827392;                 // f32  [6][4096]
  const size_t OFF_GX   = 128925696;                 // bf16 [2][300][4][32][1024]
  const size_t OFF_Y0   = 286212096;                 // bf16 [9600][2048]
  const size_t OFF_Y1   = 325533696;                 // bf16 [9600][2048]
  const size_t OFF_HBF  = 364855296;                 // bf16 [2 par][2 dir][32][1024]
  const size_t OFF_FLG  = 365117440;                 // int  [64]

  bf16*  xb    = (bf16*)(ws + OFF_XB);
  bf16*  wih0b = (bf16*)(ws + OFF_WIH0);
  bf16*  wihLb = (bf16*)(ws + OFF_WIHL);
  bf16*  whhb  = (bf16*)(ws + OFF_WHH);
  float* bsum  = (float*)(ws + OFF_BSUM);
  bf16*  gx    = (bf16*)(ws + OFF_GX);
  bf16*  y0    = (bf16*)(ws + OFF_Y0);
  bf16*  y1    = (bf16*)(ws + OFF_Y1);
  bf16*  hbuf  = (bf16*)(ws + OFF_HBF);
  int*   flags = (int*)(ws + OFF_FLG);

  auto cvt = [&](const float* s, bf16* d, size_t n) {
    int n8 = (int)(n / 8);
    int grid = (n8 + 255) / 256; if (grid > 2048) grid = 2048;
    k_cvt<<<grid, 256, 0, stream>>>(s, d, n8);
  };

  cvt(x,     xb,    (size_t)MROWS * DIN);
  cvt(w_ih0, wih0b, (size_t)2 * NG * DIN);
  cvt(w_ihL, wihLb, (size_t)2 * 2 * NG * 2048);
  cvt(w_hh0, whhb,  (size_t)2 * NG * NH);
  cvt(w_hhL, whhb + (size_t)2 * NG * NH, (size_t)4 * NG * NH);
  k_bsum<<<96, 256, 0, stream>>>(b_ih0, b_hh0, b_ihL, b_hhL, bsum);

  for (int l = 0; l < 3; ++l) {
    const bf16* A = (l == 0) ? xb : (l == 1 ? y0 : y1);
    int K = (l == 0) ? DIN : 2048;
    const bf16* Bw = (l == 0) ? wih0b : (wihLb + (size_t)(l - 1) * 2 * NG * 2048);
    k_gemm_gx<<<dim3(64, 75), 256, 0, stream>>>(A, Bw, bsum + (size_t)l * 2 * NG, gx, K);

    k_init<<<256, 256, 0, stream>>>(h0, hbuf, flags, l);

    const bf16* whh_l = whhb + (size_t)l * 2 * NG * NH;
    bf16* yout = (l == 0) ? y0 : (l == 1 ? y1 : nullptr);
    k_rec<<<64, 512, 0, stream>>>(whh_l, gx, h0, hbuf, flags, yout, dout, l);
  }
  (void)in_sizes; (void)n_in; (void)out_size; (void)ws_size;
}

// Round 5
// 4969.935 us; speedup vs baseline: 2.7046x; 1.8477x over previous
//
#include <hip/hip_runtime.h>

typedef __bf16 bf16;
typedef __attribute__((ext_vector_type(8))) __bf16 bf16x8;
typedef __attribute__((ext_vector_type(4))) float f32x4;

#define GLOBAL_AS __attribute__((address_space(1)))
#define LDS_AS __attribute__((address_space(3)))

__device__ __forceinline__ void gload_lds16(const void* g, void* l) {
  __builtin_amdgcn_global_load_lds((const GLOBAL_AS void*)g, (LDS_AS void*)l, 16, 0, 0);
}
// cache-bypassing variant (sc0|sc1 = system scope): coherent-read-through, no L1/L2 hit
__device__ __forceinline__ void gload_lds16_cc(const void* g, void* l) {
  __builtin_amdgcn_global_load_lds((const GLOBAL_AS void*)g, (LDS_AS void*)l, 16, 0, 0x11);
}

__device__ __forceinline__ f32x4 mfma16(bf16x8 a, bf16x8 b, f32x4 c) {
  return __builtin_amdgcn_mfma_f32_16x16x32_bf16(a, b, c, 0, 0, 0);
}

// ---------------- constants ----------------
#define T_SEQ 300
#define NBATCH 32
#define DIN 320
#define NH 1024
#define NG 4096              // 4*NH
#define MROWS 9600           // T_SEQ*NBATCH
#define OUT_Y 19660800       // T*B*2H
#define HN_SZ 196608         // 6*32*1024

// ---------------- f32 -> bf16 convert ----------------
__global__ __launch_bounds__(256) void k_cvt(const float* __restrict__ src,
                                             bf16* __restrict__ dst, int n8) {
  int stride = gridDim.x * blockDim.x;
  for (int i = blockIdx.x * blockDim.x + threadIdx.x; i < n8; i += stride) {
    const float* s = src + (size_t)i * 8;
    f32x4 a = *(const f32x4*)s;
    f32x4 b = *(const f32x4*)(s + 4);
    bf16x8 o;
#pragma unroll
    for (int j = 0; j < 4; ++j) { o[j] = (bf16)a[j]; o[j + 4] = (bf16)b[j]; }
    *(bf16x8*)(dst + (size_t)i * 8) = o;
  }
}

// ---------------- bias sums: bsum[l][dir][4096] = b_ih + b_hh ----------------
__global__ __launch_bounds__(256) void k_bsum(const float* __restrict__ bih0,
                                              const float* __restrict__ bhh0,
                                              const float* __restrict__ bihL,
                                              const float* __restrict__ bhhL,
                                              float* __restrict__ bsum) {
  int i = blockIdx.x * 256 + threadIdx.x;  // n = 6*4096 = 24576
  if (i < 2 * NG) bsum[i] = bih0[i] + bhh0[i];
  else            bsum[i] = bihL[i - 2 * NG] + bhhL[i - 2 * NG];
}

// ---------------- GX GEMM: gxT[dir][t][gate][b][u] = A[M,K] * W[8192,K]^T + bias ----------------
__global__ __launch_bounds__(256) void k_gemm_gx(const bf16* __restrict__ A,
                                                 const bf16* __restrict__ Bw,
                                                 const float* __restrict__ bias,
                                                 bf16* __restrict__ gxout, int K) {
  __shared__ bf16 As[128 * 32];
  __shared__ bf16 Bs[128 * 32];
  const int t = threadIdx.x;
  const int m0 = blockIdx.y * 128, n0 = blockIdx.x * 128;
  const int lane = t & 63, wid = t >> 6;
  const int wr = wid >> 1, wc = wid & 1;
  const int fr = lane & 15, fq = lane >> 4;
  f32x4 acc[4][4] = {};
  for (int k0 = 0; k0 < K; k0 += 32) {
#pragma unroll
    for (int r = 0; r < 2; ++r) {
      int idx = r * 256 + t;
      int row = idx >> 2, kk = (idx & 3) * 8;
      gload_lds16(A + (size_t)(m0 + row) * K + k0 + kk, As + (size_t)idx * 8);
      gload_lds16(Bw + (size_t)(n0 + row) * K + k0 + kk, Bs + (size_t)idx * 8);
    }
    asm volatile("s_waitcnt vmcnt(0)" ::: "memory");
    __syncthreads();
    bf16x8 af[4], bf_[4];
#pragma unroll
    for (int i2 = 0; i2 < 4; ++i2) {
      af[i2]  = *(const bf16x8*)(As + (wr * 64 + i2 * 16 + fr) * 32 + fq * 8);
      bf_[i2] = *(const bf16x8*)(Bs + (wc * 64 + i2 * 16 + fr) * 32 + fq * 8);
    }
#pragma unroll
    for (int mi = 0; mi < 4; ++mi)
#pragma unroll
      for (int ni = 0; ni < 4; ++ni)
        acc[mi][ni] = mfma16(af[mi], bf_[ni], acc[mi][ni]);
    __syncthreads();
  }
  // epilogue: add bias, scatter to gxT[dir][t][g][b][u]
#pragma unroll
  for (int ni = 0; ni < 4; ++ni) {
    int col = n0 + wc * 64 + ni * 16 + fr;
    float bv = bias[col];
    int dir = col >> 12, grow = col & (NG - 1);
    int gg = grow >> 10, uu = grow & 1023;
    bf16* base = gxout + ((size_t)dir * 300 * 4 + gg) * 32768 + uu;
#pragma unroll
    for (int mi = 0; mi < 4; ++mi) {
#pragma unroll
      for (int j = 0; j < 4; ++j) {
        int row = m0 + wr * 64 + mi * 16 + fq * 4 + j;
        int tt = row >> 5, b = row & 31;
        base[(size_t)tt * 131072 + b * 1024] = (bf16)(acc[mi][ni][j] + bv);
      }
    }
  }
}

// ---------------- per-layer init: h buffer (par 0) + flags ----------------
__global__ __launch_bounds__(256) void k_init(const float* __restrict__ h0,
                                              bf16* __restrict__ hbuf,
                                              int* __restrict__ flags, int layer) {
  int i = blockIdx.x * 256 + threadIdx.x;  // 65536 = [2 dir][32][1024]
  hbuf[i] = (bf16)h0[(size_t)layer * 65536 + i];
  if (blockIdx.x == 0 && threadIdx.x < 64) flags[threadIdx.x] = 0;
}

// ---------------- persistent recurrence: one launch per layer ----------------
// grid = 64 blocks x 512 threads. dir = bid>>5; block owns 32 hidden units.
// Wave w: K-quarter kh=w>>1, row-half rh=w&1 -> 64 gate-rows x K=256, W in 128 regs.
__global__ __launch_bounds__(512, 1) void k_rec(
    const bf16* __restrict__ whh,   // [2][4096][1024] (this layer)
    const bf16* __restrict__ gxT,   // [2][300][4][32][1024] bf16, biases folded
    const float* __restrict__ h0,   // [6][32][1024]
    bf16* __restrict__ hbuf,        // [2 par][2 dir][32][1024]
    int* __restrict__ flags,        // [64], zeroed by k_init
    bf16* __restrict__ yout,        // [9600][2048] or null (layer 2)
    float* __restrict__ dout,
    int layer) {
  __shared__ char smem_[75776];
  // [0..65536)   h tile (XOR-swizzled rows), dead after MFMA phase
  // [0..67584)   EX exchange [4 kh][128 row][33] f32 (aliases h tile)
  // [67584..75776) gx tile [4 g][32 b][32 u] bf16 = 8 KB
  float* EX = (float*)smem_;
  char* gxl = smem_ + 67584;

  const int tid = threadIdx.x;
  const int bid = blockIdx.x;
  const int dir = bid >> 5;
  const int rank = bid & 31;
  const int u0 = rank << 5;
  const int w = tid >> 6, lane = tid & 63;
  const int fr = lane & 15, fq = lane >> 4;
  const int kh = w >> 1, rh = w & 1;

  // ---- weights -> registers (64 rows x K=256 per wave = 128 regs/lane), pinned ----
  f32x4 wf[32];
#pragma unroll
  for (int rg = 0; rg < 4; ++rg) {
    int rowb = rh * 64 + rg * 16 + fr;  // block gate-row 0..127 (= g*32 + u_local)
    const bf16* Wp = whh + ((size_t)dir * 4096 + (rowb >> 5) * 1024 + u0 + (rowb & 31)) * 1024
                     + kh * 256 + fq * 8;
#pragma unroll
    for (int it = 0; it < 8; ++it) wf[rg * 8 + it] = *(const f32x4*)(Wp + it * 32);
  }
#pragma unroll
  for (int i = 0; i < 32; ++i) asm volatile("" : "+v"(wf[i]));

  // ---- cell state in registers; c init = h0 (reference's cn=hn bug) ----
  const int b_pt = tid >> 4;           // batch 0..31
  const int ul_pt = (tid & 15) << 1;   // local unit 0,2,..,30
  const int ug_pt = u0 + ul_pt;
  const size_t soff = ((size_t)layer * 2 + dir) * 32768 + (size_t)b_pt * 1024 + ug_pt;
  float c0 = h0[soff], c1 = h0[soff + 1];
  float hl0 = 0.f, hl1 = 0.f;

  // gx DMA mapping: thread -> (gate, b, 16B quarter)
  const int gg = tid >> 7, sub = tid & 127;
  const size_t gx_base0 = ((size_t)dir * 1200 + gg) * 32768
                          + (size_t)(sub >> 2) * 1024 + u0 + (sub & 3) * 8;

  // h-stage source offsets (t-invariant): linear LDS dest, inverse-swizzled source
  int srcoff[8];
#pragma unroll
  for (int r = 0; r < 8; ++r) {
    int d = r * 8192 + tid * 16;
    int row = d >> 11, colb = d & 2047;
    srcoff[r] = row * 2048 + (colb ^ ((row & 7) << 4));
  }
  const int swz = (fr & 7) << 4;

#pragma unroll 1
  for (int t = 0; t < T_SEQ; ++t) {
    const int tseq = dir ? (T_SEQ - 1 - t) : t;

    // ---- issue gx(t) DMA (8KB, cached; L2 stays warm — no per-step fence) ----
    gload_lds16(gxT + gx_base0 + (size_t)tseq * 131072, gxl + tid * 16);

    // ---- barrier: all same-dir blocks published h(t-1) ----
    if (tid < 32) {
      while (__hip_atomic_load(&flags[dir * 32 + tid], __ATOMIC_RELAXED,
                               __HIP_MEMORY_SCOPE_AGENT) < t)
        __builtin_amdgcn_s_sleep(1);
    }
    __syncthreads();   // execution order: no thread reads h before poll passes

    // ---- stage h(dir) 64KB -> LDS via coherence-point bypass loads ----
    const char* hsrc = (const char*)hbuf + (((size_t)(t & 1) * 2 + dir) << 16);
#pragma unroll
    for (int r = 0; r < 8; ++r)
      gload_lds16_cc(hsrc + srcoff[r], smem_ + r * 8192 + tid * 16);
    asm volatile("s_waitcnt vmcnt(0)" ::: "memory");
    __syncthreads();

    // ---- matvec: K-split-4, 64 MFMA from LDS(h) x reg(W); 16KB LDS read/wave ----
    f32x4 acc[4][2] = {};
    const char* hb0 = smem_ + fr * 2048;
#pragma unroll
    for (int it = 0; it < 8; ++it) {
      int col = kh * 512 + it * 64 + fq * 16;
      bf16x8 ha0 = *(const bf16x8*)(hb0 + (col ^ swz));
      bf16x8 ha1 = *(const bf16x8*)(hb0 + 32768 + (col ^ swz));
#pragma unroll
      for (int rg = 0; rg < 4; ++rg) {
        bf16x8 wv = __builtin_bit_cast(bf16x8, wf[rg * 8 + it]);
        acc[rg][0] = mfma16(ha0, wv, acc[rg][0]);
        acc[rg][1] = mfma16(ha1, wv, acc[rg][1]);
      }
    }
    __syncthreads();  // all waves done reading h tile; EX aliases it

    // ---- exchange K-partials via LDS (stride 33) ----
#pragma unroll
    for (int rg = 0; rg < 4; ++rg) {
      int rowb = rh * 64 + rg * 16 + fr;
      float* exr = EX + (size_t)(kh * 128 + rowb) * 33;
#pragma unroll
      for (int j = 0; j < 4; ++j) {
        exr[fq * 4 + j]      = acc[rg][0][j];   // batch = fq*4+j
        exr[16 + fq * 4 + j] = acc[rg][1][j];   // batch = 16+fq*4+j
      }
    }
    __syncthreads();

    // ---- pointwise: 2 (b,u) pairs/thread; sum 4 K-partials + gx; c in regs ----
    const bf16* gxb = (const bf16*)gxl;
    float hv[2]; float cc[2] = {c0, c1};
#pragma unroll
    for (int q = 0; q < 2; ++q) {
      int ul = ul_pt + q;
      float gt[4];
#pragma unroll
      for (int g2 = 0; g2 < 4; ++g2) {
        int rowb = g2 * 32 + ul;
        float s = EX[(size_t)(0 * 128 + rowb) * 33 + b_pt]
                + EX[(size_t)(1 * 128 + rowb) * 33 + b_pt]
                + EX[(size_t)(2 * 128 + rowb) * 33 + b_pt]
                + EX[(size_t)(3 * 128 + rowb) * 33 + b_pt];
        gt[g2] = s + (float)gxb[(g2 * 32 + b_pt) * 32 + ul];
      }
      float iv = fminf(fmaxf(__builtin_fmaf(0.2f, gt[0], 0.5f), 0.f), 1.f);
      float fv = fminf(fmaxf(__builtin_fmaf(0.2f, gt[1], 0.5f), 0.f), 1.f);
      float gv = fminf(fmaxf(gt[2], -1.f), 1.f);
      float ov = fminf(fmaxf(__builtin_fmaf(0.2f, gt[3], 0.5f), 0.f), 1.f);
      float c = fv * cc[q] + iv * gv;
      cc[q] = c;
      hv[q] = ov * fminf(fmaxf(c, -1.f), 1.f);
    }
    c0 = cc[0]; c1 = cc[1]; hl0 = hv[0]; hl1 = hv[1];

    // ---- publish h (volatile write-through), drain, relaxed flag, then y ----
    unsigned hp;
    { union { bf16 h[2]; unsigned u; } pk; pk.h[0] = (bf16)hv[0]; pk.h[1] = (bf16)hv[1]; hp = pk.u; }
    volatile unsigned* hdst =
        (volatile unsigned*)((char*)hbuf + (((size_t)((t + 1) & 1) * 2 + dir) << 16))
        + (((size_t)b_pt * 1024 + ug_pt) >> 1);
    *hdst = hp;
    asm volatile("s_waitcnt vmcnt(0)" ::: "memory");
    __syncthreads();   // all h stores at coherence point before flag release
    if (tid == 0)
      __hip_atomic_store(&flags[bid], t + 1, __ATOMIC_RELAXED, __HIP_MEMORY_SCOPE_AGENT);
    if (yout) {
      *(unsigned*)((char*)yout + (((size_t)tseq * 32 + b_pt) * 2048 + dir * 1024 + ug_pt) * 2) = hp;
    } else {
      float* yd = dout + ((size_t)tseq * 32 + b_pt) * 2048 + dir * 1024 + ug_pt;
      yd[0] = hv[0]; yd[1] = hv[1];
    }
  }

  // ---- final (h,c) states from registers ----
  dout[OUT_Y + soff] = hl0;
  dout[OUT_Y + soff + 1] = hl1;
  dout[OUT_Y + HN_SZ + soff] = c0;
  dout[OUT_Y + HN_SZ + soff + 1] = c1;
}

// ---------------- host launcher ----------------
extern "C" void kernel_launch(void* const* d_in, const int* in_sizes, int n_in,
                              void* d_out, int out_size, void* d_ws, size_t ws_size,
                              hipStream_t stream) {
  const float* x     = (const float*)d_in[0];
  const float* h0    = (const float*)d_in[1];
  // d_in[2] = c0: unused (reference init bug: cn = hn = h0)
  const float* w_ih0 = (const float*)d_in[3];
  const float* w_hh0 = (const float*)d_in[4];
  const float* b_ih0 = (const float*)d_in[5];
  const float* b_hh0 = (const float*)d_in[6];
  const float* w_ihL = (const float*)d_in[7];
  const float* w_hhL = (const float*)d_in[8];
  const float* b_ihL = (const float*)d_in[9];
  const float* b_hhL = (const float*)d_in[10];
  float* dout = (float*)d_out;
  char* ws = (char*)d_ws;

  // ---- workspace carve (bytes) ----
  const size_t OFF_XB   = 0;                         // bf16 [9600][320]
  const size_t OFF_WIH0 = 6144000;                   // bf16 [8192][320]
  const size_t OFF_WIHL = 11386880;                  // bf16 [2][8192][2048]
  const size_t OFF_WHH  = 78495744;                  // bf16 [6][4096][1024]
  const size_t OFF_BSUM = 128827392;                 // f32  [6][4096]
  const size_t OFF_GX   = 128925696;                 // bf16 [2][300][4][32][1024]
  const size_t OFF_Y0   = 286212096;                 // bf16 [9600][2048]
  const size_t OFF_Y1   = 325533696;                 // bf16 [9600][2048]
  const size_t OFF_HBF  = 364855296;                 // bf16 [2 par][2 dir][32][1024]
  const size_t OFF_FLG  = 365117440;                 // int  [64]

  bf16*  xb    = (bf16*)(ws + OFF_XB);
  bf16*  wih0b = (bf16*)(ws + OFF_WIH0);
  bf16*  wihLb = (bf16*)(ws + OFF_WIHL);
  bf16*  whhb  = (bf16*)(ws + OFF_WHH);
  float* bsum  = (float*)(ws + OFF_BSUM);
  bf16*  gx    = (bf16*)(ws + OFF_GX);
  bf16*  y0    = (bf16*)(ws + OFF_Y0);
  bf16*  y1    = (bf16*)(ws + OFF_Y1);
  bf16*  hbuf  = (bf16*)(ws + OFF_HBF);
  int*   flags = (int*)(ws + OFF_FLG);

  auto cvt = [&](const float* s, bf16* d, size_t n) {
    int n8 = (int)(n / 8);
    int grid = (n8 + 255) / 256; if (grid > 2048) grid = 2048;
    k_cvt<<<grid, 256, 0, stream>>>(s, d, n8);
  };

  cvt(x,     xb,    (size_t)MROWS * DIN);
  cvt(w_ih0, wih0b, (size_t)2 * NG * DIN);
  cvt(w_ihL, wihLb, (size_t)2 * 2 * NG * 2048);
  cvt(w_hh0, whhb,  (size_t)2 * NG * NH);
  cvt(w_hhL, whhb + (size_t)2 * NG * NH, (size_t)4 * NG * NH);
  k_bsum<<<96, 256, 0, stream>>>(b_ih0, b_hh0, b_ihL, b_hhL, bsum);

  for (int l = 0; l < 3; ++l) {
    const bf16* A = (l == 0) ? xb : (l == 1 ? y0 : y1);
    int K = (l == 0) ? DIN : 2048;
    const bf16* Bw = (l == 0) ? wih0b : (wihLb + (size_t)(l - 1) * 2 * NG * 2048);
    k_gemm_gx<<<dim3(64, 75), 256, 0, stream>>>(A, Bw, bsum + (size_t)l * 2 * NG, gx, K);

    k_init<<<256, 256, 0, stream>>>(h0, hbuf, flags, l);

    const bf16* whh_l = whhb + (size_t)l * 2 * NG * NH;
    bf16* yout = (l == 0) ? y0 : (l == 1 ? y1 : nullptr);
    k_rec<<<64, 512, 0, stream>>>(whh_l, gx, h0, hbuf, flags, yout, dout, l);
  }
  (void)in_sizes; (void)n_in; (void)out_size; (void)ws_size;
}